// Round 1
// baseline (1080.995 us; speedup 1.0000x reference)
//
#include <hip/hip_runtime.h>

typedef unsigned short ushort_t;
typedef unsigned int u32;
typedef unsigned long long u64;
typedef __attribute__((ext_vector_type(8))) short bf16x8;   // 8 bf16 in 4 VGPRs
typedef __attribute__((ext_vector_type(4))) float f32x4;

#define N_ROWS 65536
#define K_EMB  2048
#define D_DIM  512
// d_out float offsets (outputs concatenated in return order)
#define OFF_ZQ   0
#define OFF_IDX  33554432
#define OFF_LOSS 33619968
#define OFF_EMB  33619969
#define OFF_NCS  34668545
#define OFF_NEA  34670593
#define TAU 0.5f

__device__ __forceinline__ ushort_t f2bf(float f) {
  u32 u = __float_as_uint(f);
  u32 r = (u + 0x7fffu + ((u >> 16) & 1u)) >> 16;   // RNE
  return (ushort_t)r;
}
__device__ __forceinline__ float bf2f(ushort_t h) { return __uint_as_float(((u32)h) << 16); }
// monotone float->u32 (no NaN in data)
__device__ __forceinline__ u32 f2mono(float f) {
  u32 u = __float_as_uint(f);
  return (u & 0x80000000u) ? ~u : (u | 0x80000000u);
}
__device__ __forceinline__ float unmono(u32 m) {
  u32 u = (m & 0x80000000u) ? (m & 0x7fffffffu) : ~m;
  return __uint_as_float(u);
}
__device__ __forceinline__ void glds16(const void* g, void* l) {
  __builtin_amdgcn_global_load_lds((const __attribute__((address_space(1))) u32*)g,
                                   (__attribute__((address_space(3))) u32*)l, 16, 0, 0);
}

// ---- prep: split z_e into bf16 hi/lo (stored in d_out z_q section as scratch) ----
__global__ void prep_z_kernel(const float* __restrict__ ze, ushort_t* __restrict__ xh,
                              ushort_t* __restrict__ xl, float* __restrict__ counts,
                              float* __restrict__ lossws)
{
  int gid = blockIdx.x * 256 + threadIdx.x;          // grid 8192
  const float4* zin = (const float4*)ze;
  ushort4* xh4 = (ushort4*)xh;
  ushort4* xl4 = (ushort4*)xl;
  for (int g = gid; g < (N_ROWS * D_DIM / 4); g += 8192 * 256) {
    float4 v = zin[g];
    ushort4 h, lo;
    h.x = f2bf(v.x); lo.x = f2bf(v.x - bf2f(h.x));
    h.y = f2bf(v.y); lo.y = f2bf(v.y - bf2f(h.y));
    h.z = f2bf(v.z); lo.z = f2bf(v.z - bf2f(h.z));
    h.w = f2bf(v.w); lo.w = f2bf(v.w - bf2f(h.w));
    xh4[g] = h; xl4[g] = lo;
  }
  if (gid < K_EMB) counts[gid] = 0.0f;
  if (gid == 0) lossws[0] = 0.0f;
}

// ---- prep: split embedding, row norms ----
__global__ void prep_e_kernel(const float* __restrict__ emb, ushort_t* __restrict__ eh,
                              ushort_t* __restrict__ el, float* __restrict__ enorm)
{
  int w = threadIdx.x >> 6, l = threadIdx.x & 63;
  int k = blockIdx.x * 4 + w;                        // grid 512 -> 2048 rows
  const float4* row = (const float4*)(emb + (size_t)k * D_DIM);
  float4 a = row[l * 2], b = row[l * 2 + 1];
  ushort4 h0, h1, l0, l1;
  h0.x = f2bf(a.x); l0.x = f2bf(a.x - bf2f(h0.x));
  h0.y = f2bf(a.y); l0.y = f2bf(a.y - bf2f(h0.y));
  h0.z = f2bf(a.z); l0.z = f2bf(a.z - bf2f(h0.z));
  h0.w = f2bf(a.w); l0.w = f2bf(a.w - bf2f(h0.w));
  h1.x = f2bf(b.x); l1.x = f2bf(b.x - bf2f(h1.x));
  h1.y = f2bf(b.y); l1.y = f2bf(b.y - bf2f(h1.y));
  h1.z = f2bf(b.z); l1.z = f2bf(b.z - bf2f(h1.z));
  h1.w = f2bf(b.w); l1.w = f2bf(b.w - bf2f(h1.w));
  ((ushort4*)(eh + (size_t)k * D_DIM))[l * 2] = h0;
  ((ushort4*)(eh + (size_t)k * D_DIM))[l * 2 + 1] = h1;
  ((ushort4*)(el + (size_t)k * D_DIM))[l * 2] = l0;
  ((ushort4*)(el + (size_t)k * D_DIM))[l * 2 + 1] = l1;
  float s = a.x*a.x + a.y*a.y + a.z*a.z + a.w*a.w + b.x*b.x + b.y*b.y + b.z*b.z + b.w*b.w;
  #pragma unroll
  for (int off = 32; off >= 1; off >>= 1) s += __shfl_xor(s, off);
  if (l == 0) enorm[k] = s;
}

// ---- main distance GEMM: dist' = ||e||^2 - 2 x.e via 3-pass split-bf16 MFMA ----
// 128x128 tile, 4 waves (2x2), 16x16x32 MFMA, BK=64, XOR-swizzled LDS, global_load_lds.
// Emits per-row top-2 packed candidates (key21<<11 | col) per col-tile.
__global__ __launch_bounds__(256, 2)
void dist_gemm(const ushort_t* __restrict__ xh, const ushort_t* __restrict__ xl,
               const ushort_t* __restrict__ eh, const ushort_t* __restrict__ el,
               const float* __restrict__ enorm, u32* __restrict__ list)
{
  __shared__ ushort_t Ah[128 * 64];
  __shared__ ushort_t Al[128 * 64];
  __shared__ ushort_t Bh[128 * 64];
  __shared__ ushort_t Bl[128 * 64];
  const int t = threadIdx.x;
  const int w = t >> 6, l = t & 63;
  const int li = l & 15, lg = l >> 4;
  const int bx = blockIdx.x;
  const int rt = bx >> 4, ct = bx & 15;
  const int row0 = rt << 7, col0 = ct << 7;
  const int wr = (w >> 1) << 6, wc = (w & 1) << 6;

  f32x4 zero4 = {0.f, 0.f, 0.f, 0.f};
  f32x4 acc[4][4];
  #pragma unroll
  for (int m = 0; m < 4; ++m)
    #pragma unroll
    for (int n = 0; n < 4; ++n) acc[m][n] = zero4;

  const int Gbase = (w << 6) + l;
  for (int kit = 0; kit < 8; ++kit) {
    const int kb = kit << 7;                         // byte offset within 1024B row
    #pragma unroll
    for (int i = 0; i < 4; ++i) {
      int G = (i << 8) + Gbase;                      // granule 0..1023
      int r = G >> 3, gp = G & 7;
      int cb = gp ^ (r & 7);                         // pre-swizzled global source
      size_t gA = ((size_t)(row0 + r) << 10) + kb + (cb << 4);
      size_t gB = ((size_t)(col0 + r) << 10) + kb + (cb << 4);
      int ld = ((i << 8) + (w << 6)) << 4;           // wave-uniform LDS byte base
      glds16((const char*)xh + gA, (char*)Ah + ld);
      glds16((const char*)xl + gA, (char*)Al + ld);
      glds16((const char*)eh + gB, (char*)Bh + ld);
      glds16((const char*)el + gB, (char*)Bl + ld);
    }
    __syncthreads();
    #pragma unroll
    for (int kblk = 0; kblk < 2; ++kblk) {
      bf16x8 fah[4], fal[4], fbh[4], fbl[4];
      #pragma unroll
      for (int m = 0; m < 4; ++m) {
        int r = wr + (m << 4) + li;
        int c = (kblk << 2) + lg;
        int off = (r << 7) + ((c ^ (r & 7)) << 4);   // swizzled read
        fah[m] = *(const bf16x8*)((const char*)Ah + off);
        fal[m] = *(const bf16x8*)((const char*)Al + off);
      }
      #pragma unroll
      for (int n = 0; n < 4; ++n) {
        int r = wc + (n << 4) + li;
        int c = (kblk << 2) + lg;
        int off = (r << 7) + ((c ^ (r & 7)) << 4);
        fbh[n] = *(const bf16x8*)((const char*)Bh + off);
        fbl[n] = *(const bf16x8*)((const char*)Bl + off);
      }
      #pragma unroll
      for (int m = 0; m < 4; ++m)
        #pragma unroll
        for (int n = 0; n < 4; ++n) {
          acc[m][n] = __builtin_amdgcn_mfma_f32_16x16x32_bf16(fah[m], fbh[n], acc[m][n], 0, 0, 0);
          acc[m][n] = __builtin_amdgcn_mfma_f32_16x16x32_bf16(fah[m], fbl[n], acc[m][n], 0, 0, 0);
          acc[m][n] = __builtin_amdgcn_mfma_f32_16x16x32_bf16(fal[m], fbh[n], acc[m][n], 0, 0, 0);
        }
    }
    __syncthreads();
  }

  // epilogue: per-row top-2 over this block's 128 cols
  float en[4];
  #pragma unroll
  for (int n = 0; n < 4; ++n) en[n] = enorm[col0 + wc + (n << 4) + li];

  u32* epi = (u32*)Ah;                               // reuse LDS: [128][2 waves][2]
  #pragma unroll
  for (int m = 0; m < 4; ++m) {
    #pragma unroll
    for (int i = 0; i < 4; ++i) {
      int lrow = wr + (m << 4) + (lg << 2) + i;      // C/D: col=lane&15, row=(lane>>4)*4+reg
      u32 e1 = 0xFFFFFFFFu, e2 = 0xFFFFFFFFu;
      #pragma unroll
      for (int n = 0; n < 4; ++n) {
        float dist = en[n] - 2.0f * acc[m][n][i];
        u32 ent = ((f2mono(dist) >> 11) << 11) | (u32)(col0 + wc + (n << 4) + li);
        if (ent < e1) { e2 = e1; e1 = ent; }
        else if (ent < e2) { e2 = ent; }
      }
      #pragma unroll
      for (int off = 8; off >= 1; off >>= 1) {
        u32 o1 = __shfl_xor(e1, off);
        u32 o2 = __shfl_xor(e2, off);
        u32 m1 = min(e1, o1);
        u32 m2 = min(max(e1, o1), min(e2, o2));
        e1 = m1; e2 = m2;
      }
      if (li == 0) {
        epi[(lrow << 2) + ((w & 1) << 1) + 0] = e1;
        epi[(lrow << 2) + ((w & 1) << 1) + 1] = e2;
      }
    }
  }
  __syncthreads();
  if (t < 128) {
    u32 a1 = epi[(t << 2) + 0], a2 = epi[(t << 2) + 1];
    u32 b1 = epi[(t << 2) + 2], b2 = epi[(t << 2) + 3];
    u32 m1 = min(a1, b1);
    u32 m2 = min(max(a1, b1), min(a2, b2));
    u32* dst = list + (((size_t)(row0 + t)) << 5) + (ct << 1);
    dst[0] = m1; dst[1] = m2;
  }
}

// ---- finalize argmin: merge 32 candidates/row; fp64 rescore on near-ties ----
__global__ void finalize_kernel(const u32* __restrict__ list, const float* __restrict__ ze,
                                const float* __restrict__ emb, int* __restrict__ wsidx)
{
  int w = threadIdx.x >> 6, l = threadIdx.x & 63;
  int row = blockIdx.x * 4 + w;                      // grid 16384
  u32 ent = (l < 32) ? list[(((size_t)row) << 5) + l] : 0xFFFFFFFFu;
  u32 e1 = ent, e2 = 0xFFFFFFFFu;
  #pragma unroll
  for (int off = 32; off >= 1; off >>= 1) {
    u32 o1 = __shfl_xor(e1, off);
    u32 o2 = __shfl_xor(e2, off);
    u32 m1 = min(e1, o1);
    u32 m2 = min(max(e1, o1), min(e2, o2));
    e1 = m1; e2 = m2;
  }
  float d1 = unmono(e1 & ~2047u);
  float d2 = unmono(e2 & ~2047u);
  int idx;
  if (d2 - d1 > TAU) {
    idx = (int)(e1 & 2047u);
  } else {
    // rescore all candidates within TAU of best in fp64 (matches np fp64 argmin)
    float lim = d1 + TAU;
    double bd = 1e300; int bc = 0x7fffffff;
    const float* xr = ze + (((size_t)row) << 9);
    for (int j = 0; j < 32; ++j) {
      u32 cj = __shfl(ent, j);
      if (cj == 0xFFFFFFFFu) continue;
      if (unmono(cj & ~2047u) > lim) continue;
      int col = (int)(cj & 2047u);
      const float* er = emb + (((size_t)col) << 9);
      double s = 0.0;
      #pragma unroll
      for (int q = 0; q < 8; ++q) {
        double df = (double)xr[(l << 3) + q] - (double)er[(l << 3) + q];
        s += df * df;
      }
      #pragma unroll
      for (int off = 32; off >= 1; off >>= 1) s += __shfl_xor(s, off);
      if (s < bd || (s == bd && col < bc)) { bd = s; bc = col; }
    }
    idx = bc;
  }
  if (l == 0) wsidx[row] = idx;
}

// ---- zero segment-sum accumulator (new_embedding out section used as scratch) ----
__global__ void zesum_kernel(float* __restrict__ esum)
{
  int gid = blockIdx.x * 256 + threadIdx.x;          // grid 1024
  for (int i = gid; i < K_EMB * D_DIM; i += 1024 * 256) esum[i] = 0.0f;
}

// ---- fused: z_q gather+write, idx float, loss partials, counts & embed_sum atomics ----
__global__ void vq_fuse_kernel(const float* __restrict__ ze, const float* __restrict__ emb,
                               const int* __restrict__ wsidx, float* __restrict__ o_zq,
                               float* __restrict__ o_idx, float* __restrict__ esum,
                               float* __restrict__ counts, float* __restrict__ lossws)
{
  int t = threadIdx.x;
  int sub = t >> 7, c4 = t & 127;
  int row0 = blockIdx.x << 5;                        // grid 2048, 32 rows/block
  float lacc = 0.0f;
  for (int rr = 0; rr < 16; ++rr) {
    int row = row0 + (rr << 1) + sub;
    int idx = wsidx[row];
    float4 zv = ((const float4*)(ze + (((size_t)row) << 9)))[c4];
    float4 ev = ((const float4*)(emb + (((size_t)idx) << 9)))[c4];
    float4 q;
    q.x = zv.x + (ev.x - zv.x);
    q.y = zv.y + (ev.y - zv.y);
    q.z = zv.z + (ev.z - zv.z);
    q.w = zv.w + (ev.w - zv.w);
    ((float4*)(o_zq + (((size_t)row) << 9)))[c4] = q;
    float dx = zv.x - q.x, dy = zv.y - q.y, dz = zv.z - q.z, dw = zv.w - q.w;
    lacc += dx * dx + dy * dy + dz * dz + dw * dw;
    int base = (idx << 9) + (c4 << 2);
    atomicAdd(&esum[base + 0], zv.x);
    atomicAdd(&esum[base + 1], zv.y);
    atomicAdd(&esum[base + 2], zv.z);
    atomicAdd(&esum[base + 3], zv.w);
    if (c4 == 0) {
      atomicAdd(&counts[idx], 1.0f);
      o_idx[row] = (float)idx;
    }
  }
  #pragma unroll
  for (int off = 32; off >= 1; off >>= 1) lacc += __shfl_xor(lacc, off);
  __shared__ float ls[4];
  if ((t & 63) == 0) ls[t >> 6] = lacc;
  __syncthreads();
  if (t == 0) atomicAdd(lossws, ls[0] + ls[1] + ls[2] + ls[3]);
}

// ---- cluster-size EMA + smoothing factors + loss ----
__global__ void d1_kernel(const float* __restrict__ cs, const float* __restrict__ counts,
                          float* __restrict__ o_ncs, float* __restrict__ inv,
                          const float* __restrict__ lossws, float* __restrict__ o_loss)
{
  int t = threadIdx.x;                               // single block, 256 threads
  float ncs[8]; float s = 0.0f;
  #pragma unroll
  for (int i = 0; i < 8; ++i) {
    int k = t + (i << 8);
    float v = 0.99f * cs[k] + 0.01f * counts[k];
    ncs[i] = v; o_ncs[k] = v; s += v;
  }
  __shared__ float red[256];
  red[t] = s; __syncthreads();
  for (int h = 128; h >= 1; h >>= 1) { if (t < h) red[t] += red[t + h]; __syncthreads(); }
  float n = red[0];
  float denom = n + 2048.0f * 1e-5f;
  #pragma unroll
  for (int i = 0; i < 8; ++i) {
    int k = t + (i << 8);
    float sm = (ncs[i] + 1e-5f) / denom * n;
    inv[k] = 1.0f / sm;
  }
  if (t == 0) o_loss[0] = lossws[0] * 1.25f / 33554432.0f;
}

// ---- embed_avg EMA + new embedding ----
__global__ void d2_kernel(const float* __restrict__ ea, const float* __restrict__ inv,
                          float* __restrict__ o_emb, float* __restrict__ o_nea)
{
  int gid = blockIdx.x * 256 + threadIdx.x;          // grid 1024
  for (int i = gid; i < K_EMB * D_DIM; i += 1024 * 256) {
    float es = o_emb[i];                             // segment sum (scratch)
    float nea = 0.99f * ea[i] + 0.01f * es;
    o_nea[i] = nea;
    o_emb[i] = nea * inv[i >> 9];
  }
}

extern "C" void kernel_launch(void* const* d_in, const int* in_sizes, int n_in,
                              void* d_out, int out_size, void* d_ws, size_t ws_size,
                              hipStream_t stream)
{
  const float* ze  = (const float*)d_in[0];
  const float* emb = (const float*)d_in[1];
  const float* cs  = (const float*)d_in[2];
  const float* ea  = (const float*)d_in[3];
  float* out = (float*)d_out;
  float* o_zq   = out + OFF_ZQ;
  float* o_idx  = out + OFF_IDX;
  float* o_loss = out + OFF_LOSS;
  float* o_emb  = out + OFF_EMB;
  float* o_ncs  = out + OFF_NCS;
  float* o_nea  = out + OFF_NEA;
  // d_out self-scratch: bf16 splits of z_e live in the z_q section (exact fit),
  // top-2 candidate list lives in the tail (overwritten later by idx/loss/emb/ncs/nea).
  ushort_t* xh = (ushort_t*)d_out;                   // 67 MB
  ushort_t* xl = xh + (size_t)N_ROWS * D_DIM;        // 67 MB
  u32* list = (u32*)(out + OFF_IDX);                 // 8 MB, [65536][32]
  // workspace: eh/el (4MB) + idx ints (256KB) + counts/enorm/inv (24KB) + loss
  char* ws = (char*)d_ws;
  ushort_t* ehp = (ushort_t*)ws;
  ushort_t* elp = ehp + (size_t)K_EMB * D_DIM;
  int* wsidx    = (int*)(ws + 4194304);
  float* counts = (float*)(ws + 4194304 + 262144);
  float* enorm  = counts + 2048;
  float* inv    = enorm + 2048;
  float* lossws = inv + 2048;

  prep_z_kernel<<<8192, 256, 0, stream>>>(ze, xh, xl, counts, lossws);
  prep_e_kernel<<<512, 256, 0, stream>>>(emb, ehp, elp, enorm);
  dist_gemm<<<8192, 256, 0, stream>>>(xh, xl, ehp, elp, enorm, list);
  finalize_kernel<<<16384, 256, 0, stream>>>(list, ze, emb, wsidx);
  zesum_kernel<<<1024, 256, 0, stream>>>(o_emb);
  vq_fuse_kernel<<<2048, 256, 0, stream>>>(ze, emb, wsidx, o_zq, o_idx, o_emb, counts, lossws);
  d1_kernel<<<1, 256, 0, stream>>>(cs, counts, o_ncs, inv, lossws, o_loss);
  d2_kernel<<<1024, 256, 0, stream>>>(ea, inv, o_emb, o_nea);
}

// Round 2
// 617.161 us; speedup vs baseline: 1.7516x; 1.7516x over previous
//
#include <hip/hip_runtime.h>

typedef unsigned short ushort_t;
typedef unsigned int u32;
typedef unsigned long long u64;
typedef __attribute__((ext_vector_type(8))) short bf16x8;   // 8 bf16 in 4 VGPRs
typedef __attribute__((ext_vector_type(4))) float f32x4;

#define N_ROWS 65536
#define K_EMB  2048
#define D_DIM  512
// d_out float offsets (outputs concatenated in return order)
#define OFF_ZQ   0
#define OFF_IDX  33554432
#define OFF_LOSS 33619968
#define OFF_EMB  33619969
#define OFF_NCS  34668545
#define OFF_NEA  34670593
#define TAU 0.5f
#define CHUNK 128
#define MAXCHUNK 2560

__device__ __forceinline__ ushort_t f2bf(float f) {
  u32 u = __float_as_uint(f);
  u32 r = (u + 0x7fffu + ((u >> 16) & 1u)) >> 16;   // RNE
  return (ushort_t)r;
}
__device__ __forceinline__ float bf2f(ushort_t h) { return __uint_as_float(((u32)h) << 16); }
// monotone float->u32 (no NaN in data)
__device__ __forceinline__ u32 f2mono(float f) {
  u32 u = __float_as_uint(f);
  return (u & 0x80000000u) ? ~u : (u | 0x80000000u);
}
__device__ __forceinline__ float unmono(u32 m) {
  u32 u = (m & 0x80000000u) ? (m & 0x7fffffffu) : ~m;
  return __uint_as_float(u);
}
__device__ __forceinline__ void glds16(const void* g, void* l) {
  __builtin_amdgcn_global_load_lds((const __attribute__((address_space(1))) u32*)g,
                                   (__attribute__((address_space(3))) u32*)l, 16, 0, 0);
}

// ---- prep: split z_e into bf16 hi/lo (stored in d_out z_q section as scratch) ----
__global__ void prep_z_kernel(const float* __restrict__ ze, ushort_t* __restrict__ xh,
                              ushort_t* __restrict__ xl, float* __restrict__ counts,
                              float* __restrict__ lossws)
{
  int gid = blockIdx.x * 256 + threadIdx.x;          // grid 8192
  const float4* zin = (const float4*)ze;
  ushort4* xh4 = (ushort4*)xh;
  ushort4* xl4 = (ushort4*)xl;
  for (int g = gid; g < (N_ROWS * D_DIM / 4); g += 8192 * 256) {
    float4 v = zin[g];
    ushort4 h, lo;
    h.x = f2bf(v.x); lo.x = f2bf(v.x - bf2f(h.x));
    h.y = f2bf(v.y); lo.y = f2bf(v.y - bf2f(h.y));
    h.z = f2bf(v.z); lo.z = f2bf(v.z - bf2f(h.z));
    h.w = f2bf(v.w); lo.w = f2bf(v.w - bf2f(h.w));
    xh4[g] = h; xl4[g] = lo;
  }
  if (gid < K_EMB) counts[gid] = 0.0f;
  if (gid == 0) lossws[0] = 0.0f;
}

// ---- prep: split embedding, row norms ----
__global__ void prep_e_kernel(const float* __restrict__ emb, ushort_t* __restrict__ eh,
                              ushort_t* __restrict__ el, float* __restrict__ enorm)
{
  int w = threadIdx.x >> 6, l = threadIdx.x & 63;
  int k = blockIdx.x * 4 + w;                        // grid 512 -> 2048 rows
  const float4* row = (const float4*)(emb + (size_t)k * D_DIM);
  float4 a = row[l * 2], b = row[l * 2 + 1];
  ushort4 h0, h1, l0, l1;
  h0.x = f2bf(a.x); l0.x = f2bf(a.x - bf2f(h0.x));
  h0.y = f2bf(a.y); l0.y = f2bf(a.y - bf2f(h0.y));
  h0.z = f2bf(a.z); l0.z = f2bf(a.z - bf2f(h0.z));
  h0.w = f2bf(a.w); l0.w = f2bf(a.w - bf2f(h0.w));
  h1.x = f2bf(b.x); l1.x = f2bf(b.x - bf2f(h1.x));
  h1.y = f2bf(b.y); l1.y = f2bf(b.y - bf2f(h1.y));
  h1.z = f2bf(b.z); l1.z = f2bf(b.z - bf2f(h1.z));
  h1.w = f2bf(b.w); l1.w = f2bf(b.w - bf2f(h1.w));
  ((ushort4*)(eh + (size_t)k * D_DIM))[l * 2] = h0;
  ((ushort4*)(eh + (size_t)k * D_DIM))[l * 2 + 1] = h1;
  ((ushort4*)(el + (size_t)k * D_DIM))[l * 2] = l0;
  ((ushort4*)(el + (size_t)k * D_DIM))[l * 2 + 1] = l1;
  float s = a.x*a.x + a.y*a.y + a.z*a.z + a.w*a.w + b.x*b.x + b.y*b.y + b.z*b.z + b.w*b.w;
  #pragma unroll
  for (int off = 32; off >= 1; off >>= 1) s += __shfl_xor(s, off);
  if (l == 0) enorm[k] = s;
}

// ---- main distance GEMM: dist' = ||e||^2 - 2 x.e via 3-pass split-bf16 MFMA ----
__global__ __launch_bounds__(256, 2)
void dist_gemm(const ushort_t* __restrict__ xh, const ushort_t* __restrict__ xl,
               const ushort_t* __restrict__ eh, const ushort_t* __restrict__ el,
               const float* __restrict__ enorm, u32* __restrict__ list)
{
  __shared__ ushort_t Ah[128 * 64];
  __shared__ ushort_t Al[128 * 64];
  __shared__ ushort_t Bh[128 * 64];
  __shared__ ushort_t Bl[128 * 64];
  const int t = threadIdx.x;
  const int w = t >> 6, l = t & 63;
  const int li = l & 15, lg = l >> 4;
  const int bx = blockIdx.x;
  const int rt = bx >> 4, ct = bx & 15;
  const int row0 = rt << 7, col0 = ct << 7;
  const int wr = (w >> 1) << 6, wc = (w & 1) << 6;

  f32x4 zero4 = {0.f, 0.f, 0.f, 0.f};
  f32x4 acc[4][4];
  #pragma unroll
  for (int m = 0; m < 4; ++m)
    #pragma unroll
    for (int n = 0; n < 4; ++n) acc[m][n] = zero4;

  const int Gbase = (w << 6) + l;
  for (int kit = 0; kit < 8; ++kit) {
    const int kb = kit << 7;                         // byte offset within 1024B row
    #pragma unroll
    for (int i = 0; i < 4; ++i) {
      int G = (i << 8) + Gbase;                      // granule 0..1023
      int r = G >> 3, gp = G & 7;
      int cb = gp ^ (r & 7);                         // pre-swizzled global source
      size_t gA = ((size_t)(row0 + r) << 10) + kb + (cb << 4);
      size_t gB = ((size_t)(col0 + r) << 10) + kb + (cb << 4);
      int ld = ((i << 8) + (w << 6)) << 4;           // wave-uniform LDS byte base
      glds16((const char*)xh + gA, (char*)Ah + ld);
      glds16((const char*)xl + gA, (char*)Al + ld);
      glds16((const char*)eh + gB, (char*)Bh + ld);
      glds16((const char*)el + gB, (char*)Bl + ld);
    }
    __syncthreads();
    #pragma unroll
    for (int kblk = 0; kblk < 2; ++kblk) {
      bf16x8 fah[4], fal[4], fbh[4], fbl[4];
      #pragma unroll
      for (int m = 0; m < 4; ++m) {
        int r = wr + (m << 4) + li;
        int c = (kblk << 2) + lg;
        int off = (r << 7) + ((c ^ (r & 7)) << 4);   // swizzled read
        fah[m] = *(const bf16x8*)((const char*)Ah + off);
        fal[m] = *(const bf16x8*)((const char*)Al + off);
      }
      #pragma unroll
      for (int n = 0; n < 4; ++n) {
        int r = wc + (n << 4) + li;
        int c = (kblk << 2) + lg;
        int off = (r << 7) + ((c ^ (r & 7)) << 4);
        fbh[n] = *(const bf16x8*)((const char*)Bh + off);
        fbl[n] = *(const bf16x8*)((const char*)Bl + off);
      }
      #pragma unroll
      for (int m = 0; m < 4; ++m)
        #pragma unroll
        for (int n = 0; n < 4; ++n) {
          acc[m][n] = __builtin_amdgcn_mfma_f32_16x16x32_bf16(fah[m], fbh[n], acc[m][n], 0, 0, 0);
          acc[m][n] = __builtin_amdgcn_mfma_f32_16x16x32_bf16(fah[m], fbl[n], acc[m][n], 0, 0, 0);
          acc[m][n] = __builtin_amdgcn_mfma_f32_16x16x32_bf16(fal[m], fbh[n], acc[m][n], 0, 0, 0);
        }
    }
    __syncthreads();
  }

  float en[4];
  #pragma unroll
  for (int n = 0; n < 4; ++n) en[n] = enorm[col0 + wc + (n << 4) + li];

  u32* epi = (u32*)Ah;                               // reuse LDS: [128][2 waves][2]
  #pragma unroll
  for (int m = 0; m < 4; ++m) {
    #pragma unroll
    for (int i = 0; i < 4; ++i) {
      int lrow = wr + (m << 4) + (lg << 2) + i;      // C/D: col=lane&15, row=(lane>>4)*4+reg
      u32 e1 = 0xFFFFFFFFu, e2 = 0xFFFFFFFFu;
      #pragma unroll
      for (int n = 0; n < 4; ++n) {
        float dist = en[n] - 2.0f * acc[m][n][i];
        u32 ent = ((f2mono(dist) >> 11) << 11) | (u32)(col0 + wc + (n << 4) + li);
        if (ent < e1) { e2 = e1; e1 = ent; }
        else if (ent < e2) { e2 = ent; }
      }
      #pragma unroll
      for (int off = 8; off >= 1; off >>= 1) {
        u32 o1 = __shfl_xor(e1, off);
        u32 o2 = __shfl_xor(e2, off);
        u32 m1 = min(e1, o1);
        u32 m2 = min(max(e1, o1), min(e2, o2));
        e1 = m1; e2 = m2;
      }
      if (li == 0) {
        epi[(lrow << 2) + ((w & 1) << 1) + 0] = e1;
        epi[(lrow << 2) + ((w & 1) << 1) + 1] = e2;
      }
    }
  }
  __syncthreads();
  if (t < 128) {
    u32 a1 = epi[(t << 2) + 0], a2 = epi[(t << 2) + 1];
    u32 b1 = epi[(t << 2) + 2], b2 = epi[(t << 2) + 3];
    u32 m1 = min(a1, b1);
    u32 m2 = min(max(a1, b1), min(a2, b2));
    u32* dst = list + (((size_t)(row0 + t)) << 5) + (ct << 1);
    dst[0] = m1; dst[1] = m2;
  }
}

// ---- finalize argmin: merge 32 candidates/row; fp64 rescore on near-ties ----
// also builds the cluster histogram (counts) for the counting sort.
__global__ void finalize_kernel(const u32* __restrict__ list, const float* __restrict__ ze,
                                const float* __restrict__ emb, int* __restrict__ wsidx,
                                float* __restrict__ counts)
{
  int w = threadIdx.x >> 6, l = threadIdx.x & 63;
  int row = blockIdx.x * 4 + w;                      // grid 16384
  u32 ent = (l < 32) ? list[(((size_t)row) << 5) + l] : 0xFFFFFFFFu;
  u32 e1 = ent, e2 = 0xFFFFFFFFu;
  #pragma unroll
  for (int off = 32; off >= 1; off >>= 1) {
    u32 o1 = __shfl_xor(e1, off);
    u32 o2 = __shfl_xor(e2, off);
    u32 m1 = min(e1, o1);
    u32 m2 = min(max(e1, o1), min(e2, o2));
    e1 = m1; e2 = m2;
  }
  float d1 = unmono(e1 & ~2047u);
  float d2 = unmono(e2 & ~2047u);
  int idx;
  if (d2 - d1 > TAU) {
    idx = (int)(e1 & 2047u);
  } else {
    float lim = d1 + TAU;
    double bd = 1e300; int bc = 0x7fffffff;
    const float* xr = ze + (((size_t)row) << 9);
    for (int j = 0; j < 32; ++j) {
      u32 cj = __shfl(ent, j);
      if (cj == 0xFFFFFFFFu) continue;
      if (unmono(cj & ~2047u) > lim) continue;
      int col = (int)(cj & 2047u);
      const float* er = emb + (((size_t)col) << 9);
      double s = 0.0;
      #pragma unroll
      for (int q = 0; q < 8; ++q) {
        double df = (double)xr[(l << 3) + q] - (double)er[(l << 3) + q];
        s += df * df;
      }
      #pragma unroll
      for (int off = 32; off >= 1; off >>= 1) s += __shfl_xor(s, off);
      if (s < bd || (s == bd && col < bc)) { bd = s; bc = col; }
    }
    idx = bc;
  }
  if (l == 0) {
    wsidx[row] = idx;
    atomicAdd(&counts[idx], 1.0f);
  }
}

// ---- single-block scan: offsets from counts, zero cursors, emit chunk list ----
__global__ void scan_kernel(const float* __restrict__ counts, u32* __restrict__ offsets,
                            u32* __restrict__ cursor, u32* __restrict__ chunkinfo,
                            u32* __restrict__ ntotal)
{
  int t = threadIdx.x;                               // 1 block, 256 threads
  int c[8]; int s = 0;
  #pragma unroll
  for (int i = 0; i < 8; ++i) { c[i] = (int)counts[t * 8 + i]; s += c[i]; }
  __shared__ int ts[256];
  ts[t] = s; __syncthreads();
  for (int off = 1; off < 256; off <<= 1) {
    int v = (t >= off) ? ts[t - off] : 0;
    __syncthreads();
    ts[t] += v;
    __syncthreads();
  }
  int run = ts[t] - s;                               // exclusive prefix
  int nch[8]; int ns = 0;
  #pragma unroll
  for (int i = 0; i < 8; ++i) {
    offsets[t * 8 + i] = (u32)run;
    cursor[t * 8 + i] = 0;
    run += c[i];
    nch[i] = (c[i] + CHUNK - 1) / CHUNK;
    ns += nch[i];
  }
  __shared__ int ts2[256];
  ts2[t] = ns; __syncthreads();
  for (int off = 1; off < 256; off <<= 1) {
    int v = (t >= off) ? ts2[t - off] : 0;
    __syncthreads();
    ts2[t] += v;
    __syncthreads();
  }
  int cb = ts2[t] - ns;
  #pragma unroll
  for (int i = 0; i < 8; ++i)
    for (int cc = 0; cc < nch[i]; ++cc)
      chunkinfo[cb++] = (u32)(t * 8 + i) | ((u32)cc << 11);
  if (t == 255) *ntotal = (u32)ts2[255];
}

// ---- scatter rows into cluster-sorted order ----
__global__ void scatter_kernel(const int* __restrict__ wsidx, const u32* __restrict__ offsets,
                               u32* __restrict__ cursor, u32* __restrict__ sorted)
{
  int row = blockIdx.x * 256 + threadIdx.x;          // grid 256
  int idx = wsidx[row];
  u32 pos = atomicAdd(&cursor[idx], 1u);
  sorted[offsets[idx] + pos] = (u32)row;
}

// ---- zero segment-sum accumulator (new_embedding out section used as scratch) ----
__global__ void zesum_kernel(float* __restrict__ esum)
{
  int gid = blockIdx.x * 256 + threadIdx.x;          // grid 1024
  for (int i = gid; i < K_EMB * D_DIM; i += 1024 * 256) esum[i] = 0.0f;
}

// ---- per-chunk fused: z_q write, idx, loss, segment sum (store; atomics only if >CHUNK) ----
__global__ __launch_bounds__(256)
void zq_seg_kernel(const float* __restrict__ ze, const float* __restrict__ emb,
                   const u32* __restrict__ offsets, const float* __restrict__ counts,
                   const u32* __restrict__ sorted, const u32* __restrict__ chunkinfo,
                   const u32* __restrict__ ntotal, float* __restrict__ o_zq,
                   float* __restrict__ o_idx, float* __restrict__ esum,
                   float* __restrict__ lossws)
{
  int cid = blockIdx.x;                              // grid MAXCHUNK
  if (cid >= (int)*ntotal) return;
  u32 rec = chunkinfo[cid];
  int k = rec & 2047, c = (int)(rec >> 11);
  int ctotal = (int)counts[k];
  int base = (int)offsets[k] + c * CHUNK;
  int cnt = min(ctotal - c * CHUNK, CHUNK);
  bool multi = ctotal > CHUNK;
  int t = threadIdx.x, w = t >> 6, l = t & 63;
  __shared__ u32 srow[CHUNK];
  __shared__ float sacc[4 * 512];
  __shared__ float sloss[4];
  if (t < cnt) srow[t] = sorted[base + t];
  __syncthreads();
  const float4* e4 = (const float4*)(emb + ((size_t)k << 9));
  float4 ev0 = e4[l * 2], ev1 = e4[l * 2 + 1];
  float a0x=0,a0y=0,a0z=0,a0w=0,a1x=0,a1y=0,a1z=0,a1w=0;
  float lacc = 0.f;
  for (int r = w; r < cnt; r += 4) {
    int row = (int)srow[r];
    const float4* z4 = (const float4*)(ze + ((size_t)row << 9));
    float4 zv0 = z4[l * 2], zv1 = z4[l * 2 + 1];
    float4 q0, q1;
    q0.x = zv0.x + (ev0.x - zv0.x);
    q0.y = zv0.y + (ev0.y - zv0.y);
    q0.z = zv0.z + (ev0.z - zv0.z);
    q0.w = zv0.w + (ev0.w - zv0.w);
    q1.x = zv1.x + (ev1.x - zv1.x);
    q1.y = zv1.y + (ev1.y - zv1.y);
    q1.z = zv1.z + (ev1.z - zv1.z);
    q1.w = zv1.w + (ev1.w - zv1.w);
    float4* zq4 = (float4*)(o_zq + ((size_t)row << 9));
    zq4[l * 2] = q0; zq4[l * 2 + 1] = q1;
    float dx = zv0.x - q0.x, dy = zv0.y - q0.y, dz = zv0.z - q0.z, dw = zv0.w - q0.w;
    lacc += dx*dx + dy*dy + dz*dz + dw*dw;
    dx = zv1.x - q1.x; dy = zv1.y - q1.y; dz = zv1.z - q1.z; dw = zv1.w - q1.w;
    lacc += dx*dx + dy*dy + dz*dz + dw*dw;
    a0x += zv0.x; a0y += zv0.y; a0z += zv0.z; a0w += zv0.w;
    a1x += zv1.x; a1y += zv1.y; a1z += zv1.z; a1w += zv1.w;
    if (l == 0) o_idx[row] = (float)k;
  }
  #pragma unroll
  for (int off = 32; off >= 1; off >>= 1) lacc += __shfl_xor(lacc, off);
  if (l == 0) sloss[w] = lacc;
  float* sa = sacc + w * 512 + l * 8;
  sa[0]=a0x; sa[1]=a0y; sa[2]=a0z; sa[3]=a0w; sa[4]=a1x; sa[5]=a1y; sa[6]=a1z; sa[7]=a1w;
  __syncthreads();
  #pragma unroll
  for (int j = 0; j < 2; ++j) {
    int col = t * 2 + j;
    float v = sacc[col] + sacc[512 + col] + sacc[1024 + col] + sacc[1536 + col];
    if (multi) atomicAdd(&esum[((size_t)k << 9) + col], v);
    else       esum[((size_t)k << 9) + col] = v;
  }
  if (t == 0) atomicAdd(lossws, sloss[0] + sloss[1] + sloss[2] + sloss[3]);
}

// ---- cluster-size EMA + smoothing factors + loss ----
__global__ void d1_kernel(const float* __restrict__ cs, const float* __restrict__ counts,
                          float* __restrict__ o_ncs, float* __restrict__ inv,
                          const float* __restrict__ lossws, float* __restrict__ o_loss)
{
  int t = threadIdx.x;                               // single block, 256 threads
  float ncs[8]; float s = 0.0f;
  #pragma unroll
  for (int i = 0; i < 8; ++i) {
    int k = t + (i << 8);
    float v = 0.99f * cs[k] + 0.01f * counts[k];
    ncs[i] = v; o_ncs[k] = v; s += v;
  }
  __shared__ float red[256];
  red[t] = s; __syncthreads();
  for (int h = 128; h >= 1; h >>= 1) { if (t < h) red[t] += red[t + h]; __syncthreads(); }
  float n = red[0];
  float denom = n + 2048.0f * 1e-5f;
  #pragma unroll
  for (int i = 0; i < 8; ++i) {
    int k = t + (i << 8);
    float sm = (ncs[i] + 1e-5f) / denom * n;
    inv[k] = 1.0f / sm;
  }
  if (t == 0) o_loss[0] = lossws[0] * 1.25f / 33554432.0f;
}

// ---- embed_avg EMA + new embedding ----
__global__ void d2_kernel(const float* __restrict__ ea, const float* __restrict__ inv,
                          float* __restrict__ o_emb, float* __restrict__ o_nea)
{
  int gid = blockIdx.x * 256 + threadIdx.x;          // grid 1024
  for (int i = gid; i < K_EMB * D_DIM; i += 1024 * 256) {
    float es = o_emb[i];                             // segment sum (scratch)
    float nea = 0.99f * ea[i] + 0.01f * es;
    o_nea[i] = nea;
    o_emb[i] = nea * inv[i >> 9];
  }
}

extern "C" void kernel_launch(void* const* d_in, const int* in_sizes, int n_in,
                              void* d_out, int out_size, void* d_ws, size_t ws_size,
                              hipStream_t stream)
{
  const float* ze  = (const float*)d_in[0];
  const float* emb = (const float*)d_in[1];
  const float* cs  = (const float*)d_in[2];
  const float* ea  = (const float*)d_in[3];
  float* out = (float*)d_out;
  float* o_zq   = out + OFF_ZQ;
  float* o_idx  = out + OFF_IDX;
  float* o_loss = out + OFF_LOSS;
  float* o_emb  = out + OFF_EMB;
  float* o_ncs  = out + OFF_NCS;
  float* o_nea  = out + OFF_NEA;
  // d_out self-scratch: bf16 z_e splits live in the z_q section; the candidate
  // list lives in the output tail (consumed by finalize before zesum/zq_seg
  // overwrite those sections).
  ushort_t* xh = (ushort_t*)d_out;
  ushort_t* xl = xh + (size_t)N_ROWS * D_DIM;
  u32* list = (u32*)(out + OFF_IDX);                 // [65536][32]
  // workspace layout
  char* ws = (char*)d_ws;
  ushort_t* ehp = (ushort_t*)ws;                     // 2 MB
  ushort_t* elp = ehp + (size_t)K_EMB * D_DIM;       // 2 MB
  int* wsidx    = (int*)(ws + 4194304);              // 256 KB
  float* counts = (float*)(ws + 4194304 + 262144);   // 8 KB
  float* enorm  = counts + 2048;                     // 8 KB
  float* inv    = enorm + 2048;                      // 8 KB
  float* lossws = inv + 2048;                        // 4 B (+pad)
  u32* offsets  = (u32*)(lossws + 64);               // 8 KB
  u32* cursor   = offsets + 2048;                    // 8 KB
  u32* sorted   = cursor + 2048;                     // 256 KB
  u32* chunkinfo= sorted + 65536;                    // 10 KB
  u32* ntotal   = chunkinfo + MAXCHUNK;              // 4 B

  prep_z_kernel<<<8192, 256, 0, stream>>>(ze, xh, xl, counts, lossws);
  prep_e_kernel<<<512, 256, 0, stream>>>(emb, ehp, elp, enorm);
  dist_gemm<<<8192, 256, 0, stream>>>(xh, xl, ehp, elp, enorm, list);
  finalize_kernel<<<16384, 256, 0, stream>>>(list, ze, emb, wsidx, counts);
  scan_kernel<<<1, 256, 0, stream>>>(counts, offsets, cursor, chunkinfo, ntotal);
  scatter_kernel<<<256, 256, 0, stream>>>(wsidx, offsets, cursor, sorted);
  zesum_kernel<<<1024, 256, 0, stream>>>(o_emb);
  zq_seg_kernel<<<MAXCHUNK, 256, 0, stream>>>(ze, emb, offsets, counts, sorted,
                                              chunkinfo, ntotal, o_zq, o_idx, o_emb, lossws);
  d1_kernel<<<1, 256, 0, stream>>>(cs, counts, o_ncs, inv, lossws, o_loss);
  d2_kernel<<<1024, 256, 0, stream>>>(ea, inv, o_emb, o_nea);
}

// Round 3
// 415.441 us; speedup vs baseline: 2.6020x; 1.4856x over previous
//
#include <hip/hip_runtime.h>

typedef unsigned short ushort_t;
typedef unsigned int u32;
typedef unsigned long long u64;
typedef __attribute__((ext_vector_type(8))) short bf16x8;   // 8 bf16 in 4 VGPRs
typedef __attribute__((ext_vector_type(4))) float f32x4;

#define N_ROWS 65536
#define K_EMB  2048
#define D_DIM  512
// d_out float offsets (outputs concatenated in return order)
#define OFF_ZQ   0
#define OFF_IDX  33554432
#define OFF_LOSS 33619968
#define OFF_EMB  33619969
#define OFF_NCS  34668545
#define OFF_NEA  34670593
#define TAU 1.5f
#define CHUNK 128
#define MAXCHUNK 2560

__device__ __forceinline__ ushort_t f2bf(float f) {
  u32 u = __float_as_uint(f);
  u32 r = (u + 0x7fffu + ((u >> 16) & 1u)) >> 16;   // RNE
  return (ushort_t)r;
}
__device__ __forceinline__ float bf2f(ushort_t h) { return __uint_as_float(((u32)h) << 16); }
// monotone float->u32 (no NaN in data)
__device__ __forceinline__ u32 f2mono(float f) {
  u32 u = __float_as_uint(f);
  return (u & 0x80000000u) ? ~u : (u | 0x80000000u);
}
__device__ __forceinline__ float unmono(u32 m) {
  u32 u = (m & 0x80000000u) ? (m & 0x7fffffffu) : ~m;
  return __uint_as_float(u);
}
__device__ __forceinline__ void glds16(const void* g, void* l) {
  __builtin_amdgcn_global_load_lds((const __attribute__((address_space(1))) u32*)g,
                                   (__attribute__((address_space(3))) u32*)l, 16, 0, 0);
}

// ---- prep: bf16 round of z_e (stored in d_out z_q section as scratch) ----
__global__ void prep_z_kernel(const float* __restrict__ ze, ushort_t* __restrict__ xh,
                              float* __restrict__ counts, float* __restrict__ lossws)
{
  int gid = blockIdx.x * 256 + threadIdx.x;          // grid 8192
  const float4* zin = (const float4*)ze;
  ushort4* xh4 = (ushort4*)xh;
  for (int g = gid; g < (N_ROWS * D_DIM / 4); g += 8192 * 256) {
    float4 v = zin[g];
    ushort4 h;
    h.x = f2bf(v.x); h.y = f2bf(v.y); h.z = f2bf(v.z); h.w = f2bf(v.w);
    xh4[g] = h;
  }
  if (gid < K_EMB) counts[gid] = 0.0f;
  if (gid == 0) lossws[0] = 0.0f;
}

// ---- prep: bf16 round of embedding + fp32 row norms ----
__global__ void prep_e_kernel(const float* __restrict__ emb, ushort_t* __restrict__ eh,
                              float* __restrict__ enorm)
{
  int w = threadIdx.x >> 6, l = threadIdx.x & 63;
  int k = blockIdx.x * 4 + w;                        // grid 512 -> 2048 rows
  const float4* row = (const float4*)(emb + (size_t)k * D_DIM);
  float4 a = row[l * 2], b = row[l * 2 + 1];
  ushort4 h0, h1;
  h0.x = f2bf(a.x); h0.y = f2bf(a.y); h0.z = f2bf(a.z); h0.w = f2bf(a.w);
  h1.x = f2bf(b.x); h1.y = f2bf(b.y); h1.z = f2bf(b.z); h1.w = f2bf(b.w);
  ((ushort4*)(eh + (size_t)k * D_DIM))[l * 2] = h0;
  ((ushort4*)(eh + (size_t)k * D_DIM))[l * 2 + 1] = h1;
  float s = a.x*a.x + a.y*a.y + a.z*a.z + a.w*a.w + b.x*b.x + b.y*b.y + b.z*b.z + b.w*b.w;
  #pragma unroll
  for (int off = 32; off >= 1; off >>= 1) s += __shfl_xor(s, off);
  if (l == 0) enorm[k] = s;
}

// merge two ascending quads (s,o), keep 4 smallest ascending in s
#define MERGE4(s1,s2,s3,s4,o1,o2,o3,o4) do {                        \
    u32 x1 = min(s1,o4), x2 = min(s2,o3), x3 = min(s3,o2), x4 = min(s4,o1); \
    u32 t1 = min(x1,x3), t3 = max(x1,x3), t2 = min(x2,x4), t4 = max(x2,x4); \
    s1 = min(t1,t2); s2 = max(t1,t2); s3 = min(t3,t4); s4 = max(t3,t4);     \
  } while (0)

// ---- main distance GEMM: screen = ||e||^2 - 2 xh.eh via single-pass bf16 MFMA ----
// 128x128 tile, 4 waves (2x2), 16x16x32 MFMA, BK=64, XOR-swizzled LDS, global_load_lds.
// Emits per-row top-4 packed candidates (key21<<11 | col) per 128-col tile.
__global__ __launch_bounds__(256, 4)
void dist_gemm(const ushort_t* __restrict__ xh, const ushort_t* __restrict__ eh,
               const float* __restrict__ enorm, u32* __restrict__ list)
{
  __shared__ ushort_t Ah[128 * 64];
  __shared__ ushort_t Bh[128 * 64];
  const int t = threadIdx.x;
  const int w = t >> 6, l = t & 63;
  const int li = l & 15, lg = l >> 4;
  const int bx = blockIdx.x;
  const int rt = bx >> 4, ct = bx & 15;
  const int row0 = rt << 7, col0 = ct << 7;
  const int wr = (w >> 1) << 6, wc = (w & 1) << 6;

  f32x4 zero4 = {0.f, 0.f, 0.f, 0.f};
  f32x4 acc[4][4];
  #pragma unroll
  for (int m = 0; m < 4; ++m)
    #pragma unroll
    for (int n = 0; n < 4; ++n) acc[m][n] = zero4;

  const int Gbase = (w << 6) + l;
  for (int kit = 0; kit < 8; ++kit) {
    const int kb = kit << 7;                         // byte offset within 1024B row
    #pragma unroll
    for (int i = 0; i < 4; ++i) {
      int G = (i << 8) + Gbase;                      // granule 0..1023
      int r = G >> 3, gp = G & 7;
      int cb = gp ^ (r & 7);                         // pre-swizzled global source
      size_t gA = ((size_t)(row0 + r) << 10) + kb + (cb << 4);
      size_t gB = ((size_t)(col0 + r) << 10) + kb + (cb << 4);
      int ld = ((i << 8) + (w << 6)) << 4;           // wave-uniform LDS byte base
      glds16((const char*)xh + gA, (char*)Ah + ld);
      glds16((const char*)eh + gB, (char*)Bh + ld);
    }
    __syncthreads();
    #pragma unroll
    for (int kblk = 0; kblk < 2; ++kblk) {
      bf16x8 fah[4], fbh[4];
      #pragma unroll
      for (int m = 0; m < 4; ++m) {
        int r = wr + (m << 4) + li;
        int c = (kblk << 2) + lg;
        int off = (r << 7) + ((c ^ (r & 7)) << 4);   // swizzled read
        fah[m] = *(const bf16x8*)((const char*)Ah + off);
      }
      #pragma unroll
      for (int n = 0; n < 4; ++n) {
        int r = wc + (n << 4) + li;
        int c = (kblk << 2) + lg;
        int off = (r << 7) + ((c ^ (r & 7)) << 4);
        fbh[n] = *(const bf16x8*)((const char*)Bh + off);
      }
      #pragma unroll
      for (int m = 0; m < 4; ++m)
        #pragma unroll
        for (int n = 0; n < 4; ++n)
          acc[m][n] = __builtin_amdgcn_mfma_f32_16x16x32_bf16(fah[m], fbh[n], acc[m][n], 0, 0, 0);
    }
    __syncthreads();
  }

  // epilogue: per-row top-4 over this block's 128 cols
  float en[4];
  #pragma unroll
  for (int n = 0; n < 4; ++n) en[n] = enorm[col0 + wc + (n << 4) + li];

  u32* epi = (u32*)Ah;                               // reuse LDS: [128 rows][2 waves][4]
  #pragma unroll
  for (int m = 0; m < 4; ++m) {
    #pragma unroll
    for (int i = 0; i < 4; ++i) {
      int lrow = wr + (m << 4) + (lg << 2) + i;      // C/D: col=lane&15, row=(lane>>4)*4+reg
      u32 s1 = 0xFFFFFFFFu, s2 = 0xFFFFFFFFu, s3 = 0xFFFFFFFFu, s4 = 0xFFFFFFFFu;
      #pragma unroll
      for (int n = 0; n < 4; ++n) {
        float dist = en[n] - 2.0f * acc[m][n][i];
        u32 ent = ((f2mono(dist) >> 11) << 11) | (u32)(col0 + wc + (n << 4) + li);
        if (ent < s1)      { s4 = s3; s3 = s2; s2 = s1; s1 = ent; }
        else if (ent < s2) { s4 = s3; s3 = s2; s2 = ent; }
        else if (ent < s3) { s4 = s3; s3 = ent; }
        else if (ent < s4) { s4 = ent; }
      }
      #pragma unroll
      for (int off = 8; off >= 1; off >>= 1) {
        u32 o1 = __shfl_xor(s1, off);
        u32 o2 = __shfl_xor(s2, off);
        u32 o3 = __shfl_xor(s3, off);
        u32 o4 = __shfl_xor(s4, off);
        MERGE4(s1, s2, s3, s4, o1, o2, o3, o4);
      }
      if (li == 0) {
        u32* p = epi + (lrow << 3) + ((w & 1) << 2);
        p[0] = s1; p[1] = s2; p[2] = s3; p[3] = s4;
      }
    }
  }
  __syncthreads();
  if (t < 128) {
    u32* pa = epi + (t << 3);
    u32 s1 = pa[0], s2 = pa[1], s3 = pa[2], s4 = pa[3];
    u32 o1 = pa[4], o2 = pa[5], o3 = pa[6], o4 = pa[7];
    MERGE4(s1, s2, s3, s4, o1, o2, o3, o4);
    uint4 v; v.x = s1; v.y = s2; v.z = s3; v.w = s4;
    *(uint4*)(list + (((size_t)(row0 + t)) << 6) + (ct << 2)) = v;
  }
}

// ---- finalize argmin: merge 64 candidates/row; fp64 rescore on near-ties ----
// also builds the cluster histogram (counts) for the counting sort.
__global__ void finalize_kernel(const u32* __restrict__ list, const float* __restrict__ ze,
                                const float* __restrict__ emb, int* __restrict__ wsidx,
                                float* __restrict__ counts)
{
  int w = threadIdx.x >> 6, l = threadIdx.x & 63;
  int row = blockIdx.x * 4 + w;                      // grid 16384
  u32 ent = list[(((size_t)row) << 6) + l];
  u32 e1 = ent;
  #pragma unroll
  for (int off = 32; off >= 1; off >>= 1) e1 = min(e1, __shfl_xor(e1, off));
  float d1 = unmono(e1 & ~2047u);
  float dl = unmono(ent & ~2047u);
  u64 mask = __ballot(dl < d1 + TAU);
  int idx;
  if (__popcll(mask) <= 1) {
    idx = (int)(e1 & 2047u);
  } else {
    // rescore all near candidates in fp64 (matches np argmin incl. tie-break)
    double bd = 1e300; int bc = 0x7fffffff;
    const float* xr = ze + (((size_t)row) << 9);
    u64 mm = mask;
    while (mm) {
      int j = (int)(__ffsll((long long)mm) - 1);
      mm &= mm - 1;
      u32 cj = __shfl(ent, j);
      int col = (int)(cj & 2047u);
      const float* er = emb + (((size_t)col) << 9);
      double s = 0.0;
      #pragma unroll
      for (int q = 0; q < 8; ++q) {
        double df = (double)xr[(l << 3) + q] - (double)er[(l << 3) + q];
        s += df * df;
      }
      #pragma unroll
      for (int off = 32; off >= 1; off >>= 1) s += __shfl_xor(s, off);
      if (s < bd || (s == bd && col < bc)) { bd = s; bc = col; }
    }
    idx = bc;
  }
  if (l == 0) {
    wsidx[row] = idx;
    atomicAdd(&counts[idx], 1.0f);
  }
}

// ---- single-block scan: offsets from counts, zero cursors, emit chunk list ----
__global__ void scan_kernel(const float* __restrict__ counts, u32* __restrict__ offsets,
                            u32* __restrict__ cursor, u32* __restrict__ chunkinfo,
                            u32* __restrict__ ntotal)
{
  int t = threadIdx.x;                               // 1 block, 256 threads
  int c[8]; int s = 0;
  #pragma unroll
  for (int i = 0; i < 8; ++i) { c[i] = (int)counts[t * 8 + i]; s += c[i]; }
  __shared__ int ts[256];
  ts[t] = s; __syncthreads();
  for (int off = 1; off < 256; off <<= 1) {
    int v = (t >= off) ? ts[t - off] : 0;
    __syncthreads();
    ts[t] += v;
    __syncthreads();
  }
  int run = ts[t] - s;                               // exclusive prefix
  int nch[8]; int ns = 0;
  #pragma unroll
  for (int i = 0; i < 8; ++i) {
    offsets[t * 8 + i] = (u32)run;
    cursor[t * 8 + i] = 0;
    run += c[i];
    nch[i] = (c[i] + CHUNK - 1) / CHUNK;
    ns += nch[i];
  }
  __shared__ int ts2[256];
  ts2[t] = ns; __syncthreads();
  for (int off = 1; off < 256; off <<= 1) {
    int v = (t >= off) ? ts2[t - off] : 0;
    __syncthreads();
    ts2[t] += v;
    __syncthreads();
  }
  int cb = ts2[t] - ns;
  #pragma unroll
  for (int i = 0; i < 8; ++i)
    for (int cc = 0; cc < nch[i]; ++cc)
      chunkinfo[cb++] = (u32)(t * 8 + i) | ((u32)cc << 11);
  if (t == 255) *ntotal = (u32)ts2[255];
}

// ---- scatter rows into cluster-sorted order ----
__global__ void scatter_kernel(const int* __restrict__ wsidx, const u32* __restrict__ offsets,
                               u32* __restrict__ cursor, u32* __restrict__ sorted)
{
  int row = blockIdx.x * 256 + threadIdx.x;          // grid 256
  int idx = wsidx[row];
  u32 pos = atomicAdd(&cursor[idx], 1u);
  sorted[offsets[idx] + pos] = (u32)row;
}

// ---- zero segment-sum accumulator (new_embedding out section used as scratch) ----
__global__ void zesum_kernel(float* __restrict__ esum)
{
  int gid = blockIdx.x * 256 + threadIdx.x;          // grid 1024
  for (int i = gid; i < K_EMB * D_DIM; i += 1024 * 256) esum[i] = 0.0f;
}

// ---- per-chunk fused: z_q write, idx, loss, segment sum (store; atomics only if >CHUNK) ----
__global__ __launch_bounds__(256)
void zq_seg_kernel(const float* __restrict__ ze, const float* __restrict__ emb,
                   const u32* __restrict__ offsets, const float* __restrict__ counts,
                   const u32* __restrict__ sorted, const u32* __restrict__ chunkinfo,
                   const u32* __restrict__ ntotal, float* __restrict__ o_zq,
                   float* __restrict__ o_idx, float* __restrict__ esum,
                   float* __restrict__ lossws)
{
  int cid = blockIdx.x;                              // grid MAXCHUNK
  if (cid >= (int)*ntotal) return;
  u32 rec = chunkinfo[cid];
  int k = rec & 2047, c = (int)(rec >> 11);
  int ctotal = (int)counts[k];
  int base = (int)offsets[k] + c * CHUNK;
  int cnt = min(ctotal - c * CHUNK, CHUNK);
  bool multi = ctotal > CHUNK;
  int t = threadIdx.x, w = t >> 6, l = t & 63;
  __shared__ u32 srow[CHUNK];
  __shared__ float sacc[4 * 512];
  __shared__ float sloss[4];
  if (t < cnt) srow[t] = sorted[base + t];
  __syncthreads();
  const float4* e4 = (const float4*)(emb + ((size_t)k << 9));
  float4 ev0 = e4[l * 2], ev1 = e4[l * 2 + 1];
  float a0x=0,a0y=0,a0z=0,a0w=0,a1x=0,a1y=0,a1z=0,a1w=0;
  float lacc = 0.f;
  for (int r = w; r < cnt; r += 4) {
    int row = (int)srow[r];
    const float4* z4 = (const float4*)(ze + ((size_t)row << 9));
    float4 zv0 = z4[l * 2], zv1 = z4[l * 2 + 1];
    float4 q0, q1;
    q0.x = zv0.x + (ev0.x - zv0.x);
    q0.y = zv0.y + (ev0.y - zv0.y);
    q0.z = zv0.z + (ev0.z - zv0.z);
    q0.w = zv0.w + (ev0.w - zv0.w);
    q1.x = zv1.x + (ev1.x - zv1.x);
    q1.y = zv1.y + (ev1.y - zv1.y);
    q1.z = zv1.z + (ev1.z - zv1.z);
    q1.w = zv1.w + (ev1.w - zv1.w);
    float4* zq4 = (float4*)(o_zq + ((size_t)row << 9));
    zq4[l * 2] = q0; zq4[l * 2 + 1] = q1;
    float dx = zv0.x - q0.x, dy = zv0.y - q0.y, dz = zv0.z - q0.z, dw = zv0.w - q0.w;
    lacc += dx*dx + dy*dy + dz*dz + dw*dw;
    dx = zv1.x - q1.x; dy = zv1.y - q1.y; dz = zv1.z - q1.z; dw = zv1.w - q1.w;
    lacc += dx*dx + dy*dy + dz*dz + dw*dw;
    a0x += zv0.x; a0y += zv0.y; a0z += zv0.z; a0w += zv0.w;
    a1x += zv1.x; a1y += zv1.y; a1z += zv1.z; a1w += zv1.w;
    if (l == 0) o_idx[row] = (float)k;
  }
  #pragma unroll
  for (int off = 32; off >= 1; off >>= 1) lacc += __shfl_xor(lacc, off);
  if (l == 0) sloss[w] = lacc;
  float* sa = sacc + w * 512 + l * 8;
  sa[0]=a0x; sa[1]=a0y; sa[2]=a0z; sa[3]=a0w; sa[4]=a1x; sa[5]=a1y; sa[6]=a1z; sa[7]=a1w;
  __syncthreads();
  #pragma unroll
  for (int j = 0; j < 2; ++j) {
    int col = t * 2 + j;
    float v = sacc[col] + sacc[512 + col] + sacc[1024 + col] + sacc[1536 + col];
    if (multi) atomicAdd(&esum[((size_t)k << 9) + col], v);
    else       esum[((size_t)k << 9) + col] = v;
  }
  if (t == 0) atomicAdd(lossws, sloss[0] + sloss[1] + sloss[2] + sloss[3]);
}

// ---- cluster-size EMA + smoothing factors + loss ----
__global__ void d1_kernel(const float* __restrict__ cs, const float* __restrict__ counts,
                          float* __restrict__ o_ncs, float* __restrict__ inv,
                          const float* __restrict__ lossws, float* __restrict__ o_loss)
{
  int t = threadIdx.x;                               // single block, 256 threads
  float ncs[8]; float s = 0.0f;
  #pragma unroll
  for (int i = 0; i < 8; ++i) {
    int k = t + (i << 8);
    float v = 0.99f * cs[k] + 0.01f * counts[k];
    ncs[i] = v; o_ncs[k] = v; s += v;
  }
  __shared__ float red[256];
  red[t] = s; __syncthreads();
  for (int h = 128; h >= 1; h >>= 1) { if (t < h) red[t] += red[t + h]; __syncthreads(); }
  float n = red[0];
  float denom = n + 2048.0f * 1e-5f;
  #pragma unroll
  for (int i = 0; i < 8; ++i) {
    int k = t + (i << 8);
    float sm = (ncs[i] + 1e-5f) / denom * n;
    inv[k] = 1.0f / sm;
  }
  if (t == 0) o_loss[0] = lossws[0] * 1.25f / 33554432.0f;
}

// ---- embed_avg EMA + new embedding ----
__global__ void d2_kernel(const float* __restrict__ ea, const float* __restrict__ inv,
                          float* __restrict__ o_emb, float* __restrict__ o_nea)
{
  int gid = blockIdx.x * 256 + threadIdx.x;          // grid 1024
  for (int i = gid; i < K_EMB * D_DIM; i += 1024 * 256) {
    float es = o_emb[i];                             // segment sum (scratch)
    float nea = 0.99f * ea[i] + 0.01f * es;
    o_nea[i] = nea;
    o_emb[i] = nea * inv[i >> 9];
  }
}

extern "C" void kernel_launch(void* const* d_in, const int* in_sizes, int n_in,
                              void* d_out, int out_size, void* d_ws, size_t ws_size,
                              hipStream_t stream)
{
  const float* ze  = (const float*)d_in[0];
  const float* emb = (const float*)d_in[1];
  const float* cs  = (const float*)d_in[2];
  const float* ea  = (const float*)d_in[3];
  float* out = (float*)d_out;
  float* o_zq   = out + OFF_ZQ;
  float* o_idx  = out + OFF_IDX;
  float* o_loss = out + OFF_LOSS;
  float* o_emb  = out + OFF_EMB;
  float* o_ncs  = out + OFF_NCS;
  float* o_nea  = out + OFF_NEA;
  // d_out self-scratch, all inside the 134 MB z_q section (consumed before
  // zq_seg overwrites it): xh = bf16 z_e at offset 0 (64 MB), candidate list
  // at float offset 16M (16 MB, [65536][64] u32).
  ushort_t* xh = (ushort_t*)d_out;
  u32* list = (u32*)(out + 16777216);
  // workspace layout
  char* ws = (char*)d_ws;
  ushort_t* ehp = (ushort_t*)ws;                     // 2 MB
  int* wsidx    = (int*)(ws + 2097152);              // 256 KB
  float* counts = (float*)(ws + 2097152 + 262144);   // 8 KB
  float* enorm  = counts + 2048;                     // 8 KB
  float* inv    = enorm + 2048;                      // 8 KB
  float* lossws = inv + 2048;                        // 4 B (+pad)
  u32* offsets  = (u32*)(lossws + 64);               // 8 KB
  u32* cursor   = offsets + 2048;                    // 8 KB
  u32* sorted   = cursor + 2048;                     // 256 KB
  u32* chunkinfo= sorted + 65536;                    // 10 KB
  u32* ntotal   = chunkinfo + MAXCHUNK;              // 4 B

  prep_z_kernel<<<8192, 256, 0, stream>>>(ze, xh, counts, lossws);
  prep_e_kernel<<<512, 256, 0, stream>>>(emb, ehp, enorm);
  dist_gemm<<<8192, 256, 0, stream>>>(xh, ehp, enorm, list);
  finalize_kernel<<<16384, 256, 0, stream>>>(list, ze, emb, wsidx, counts);
  scan_kernel<<<1, 256, 0, stream>>>(counts, offsets, cursor, chunkinfo, ntotal);
  scatter_kernel<<<256, 256, 0, stream>>>(wsidx, offsets, cursor, sorted);
  zesum_kernel<<<1024, 256, 0, stream>>>(o_emb);
  zq_seg_kernel<<<MAXCHUNK, 256, 0, stream>>>(ze, emb, offsets, counts, sorted,
                                              chunkinfo, ntotal, o_zq, o_idx, o_emb, lossws);
  d1_kernel<<<1, 256, 0, stream>>>(cs, counts, o_ncs, inv, lossws, o_loss);
  d2_kernel<<<1024, 256, 0, stream>>>(ea, inv, o_emb, o_nea);
}

// Round 4
// 352.315 us; speedup vs baseline: 3.0683x; 1.1792x over previous
//
#include <hip/hip_runtime.h>

typedef unsigned short ushort_t;
typedef unsigned int u32;
typedef unsigned long long u64;
typedef __attribute__((ext_vector_type(8))) short bf16x8;   // 8 bf16 in 4 VGPRs
typedef __attribute__((ext_vector_type(4))) float f32x4;

#define N_ROWS 65536
#define K_EMB  2048
#define D_DIM  512
// d_out float offsets (outputs concatenated in return order)
#define OFF_ZQ   0
#define OFF_IDX  33554432
#define OFF_LOSS 33619968
#define OFF_EMB  33619969
#define OFF_NCS  34668545
#define OFF_NEA  34670593
#define TAU 1.5f
#define CHUNK 128
#define MAXCHUNK 2560

__device__ __forceinline__ ushort_t f2bf(float f) {
  u32 u = __float_as_uint(f);
  u32 r = (u + 0x7fffu + ((u >> 16) & 1u)) >> 16;   // RNE
  return (ushort_t)r;
}
__device__ __forceinline__ void glds16(const void* g, void* l) {
  __builtin_amdgcn_global_load_lds((const __attribute__((address_space(1))) u32*)g,
                                   (__attribute__((address_space(3))) u32*)l, 16, 0, 0);
}

// merge two ascending quads (s,o), keep 4 smallest ascending in s
#define MERGE4(s1,s2,s3,s4,o1,o2,o3,o4) do {                        \
    u32 x1 = min(s1,o4), x2 = min(s2,o3), x3 = min(s3,o2), x4 = min(s4,o1); \
    u32 t1 = min(x1,x3), t3 = max(x1,x3), t2 = min(x2,x4), t4 = max(x2,x4); \
    s1 = min(t1,t2); s2 = max(t1,t2); s3 = min(t3,t4); s4 = max(t3,t4);     \
  } while (0)

// ---- prep: bf16 round of z_e (stored in d_out z_q section as scratch) ----
__global__ void prep_z_kernel(const float* __restrict__ ze, ushort_t* __restrict__ xh,
                              float* __restrict__ counts, float* __restrict__ lossws)
{
  int gid = blockIdx.x * 256 + threadIdx.x;          // grid 8192
  const float4* zin = (const float4*)ze;
  ushort4* xh4 = (ushort4*)xh;
  for (int g = gid; g < (N_ROWS * D_DIM / 4); g += 8192 * 256) {
    float4 v = zin[g];
    ushort4 h;
    h.x = f2bf(v.x); h.y = f2bf(v.y); h.z = f2bf(v.z); h.w = f2bf(v.w);
    xh4[g] = h;
  }
  if (gid < K_EMB) counts[gid] = 0.0f;
  if (gid == 0) lossws[0] = 0.0f;
}

// ---- prep: bf16 round of embedding + fp32 row norms ----
__global__ void prep_e_kernel(const float* __restrict__ emb, ushort_t* __restrict__ eh,
                              float* __restrict__ enorm)
{
  int w = threadIdx.x >> 6, l = threadIdx.x & 63;
  int k = blockIdx.x * 4 + w;                        // grid 512 -> 2048 rows
  const float4* row = (const float4*)(emb + (size_t)k * D_DIM);
  float4 a = row[l * 2], b = row[l * 2 + 1];
  ushort4 h0, h1;
  h0.x = f2bf(a.x); h0.y = f2bf(a.y); h0.z = f2bf(a.z); h0.w = f2bf(a.w);
  h1.x = f2bf(b.x); h1.y = f2bf(b.y); h1.z = f2bf(b.z); h1.w = f2bf(b.w);
  ((ushort4*)(eh + (size_t)k * D_DIM))[l * 2] = h0;
  ((ushort4*)(eh + (size_t)k * D_DIM))[l * 2 + 1] = h1;
  float s = a.x*a.x + a.y*a.y + a.z*a.z + a.w*a.w + b.x*b.x + b.y*b.y + b.z*b.z + b.w*b.w;
  #pragma unroll
  for (int off = 32; off >= 1; off >>= 1) s += __shfl_xor(s, off);
  if (l == 0) enorm[k] = s;
}

// ---- main distance GEMM: row-stripe blocks, per-lane running top-4 ----
// grid 512: each block = 128 rows x all 2048 cols, 16 col-tiles of 128.
// 4 waves (2x2), 16x16x32 MFMA, BK=64, XOR-swizzled LDS, global_load_lds.
// Keys are raw fp32 bits (all dists positive => bit-order == value-order),
// top21 bits | col11. Emits one uint4 (row top-4) per row.
__global__ __launch_bounds__(256, 2)
void dist_gemm(const ushort_t* __restrict__ xh, const ushort_t* __restrict__ eh,
               const float* __restrict__ enorm, uint4* __restrict__ list)
{
  __shared__ ushort_t Ah[128 * 64];
  __shared__ ushort_t Bh[128 * 64];
  const int t = threadIdx.x;
  const int w = t >> 6, l = t & 63;
  const int li = l & 15, lg = l >> 4;
  const int row0 = blockIdx.x << 7;
  const int wr = (w >> 1) << 6, wc = (w & 1) << 6;

  u32 cand[16][4];
  #pragma unroll
  for (int mi = 0; mi < 16; ++mi) {
    cand[mi][0] = 0xFFFFFFFFu; cand[mi][1] = 0xFFFFFFFFu;
    cand[mi][2] = 0xFFFFFFFFu; cand[mi][3] = 0xFFFFFFFFu;
  }

  const int Gbase = (w << 6) + l;

  for (int ct = 0; ct < 16; ++ct) {
    const int col0 = ct << 7;
    float en0 = enorm[col0 + wc + 0  + li];
    float en1 = enorm[col0 + wc + 16 + li];
    float en2 = enorm[col0 + wc + 32 + li];
    float en3 = enorm[col0 + wc + 48 + li];

    f32x4 acc[4][4];
    #pragma unroll
    for (int m = 0; m < 4; ++m)
      #pragma unroll
      for (int n = 0; n < 4; ++n) acc[m][n] = (f32x4){0.f, 0.f, 0.f, 0.f};

    for (int kit = 0; kit < 8; ++kit) {
      const int kb = kit << 7;                       // byte offset within 1024B row
      #pragma unroll
      for (int i = 0; i < 4; ++i) {
        int G = (i << 8) + Gbase;                    // granule 0..1023
        int r = G >> 3, gp = G & 7;
        int cb = gp ^ (r & 7);                       // pre-swizzled global source
        size_t gA = ((size_t)(row0 + r) << 10) + kb + (cb << 4);
        size_t gB = ((size_t)(col0 + r) << 10) + kb + (cb << 4);
        int ld = ((i << 8) + (w << 6)) << 4;         // wave-uniform LDS byte base
        glds16((const char*)xh + gA, (char*)Ah + ld);
        glds16((const char*)eh + gB, (char*)Bh + ld);
      }
      __syncthreads();
      #pragma unroll
      for (int kblk = 0; kblk < 2; ++kblk) {
        bf16x8 fah[4], fbh[4];
        #pragma unroll
        for (int m = 0; m < 4; ++m) {
          int r = wr + (m << 4) + li;
          int c = (kblk << 2) + lg;
          int off = (r << 7) + ((c ^ (r & 7)) << 4); // swizzled read
          fah[m] = *(const bf16x8*)((const char*)Ah + off);
        }
        #pragma unroll
        for (int n = 0; n < 4; ++n) {
          int r = wc + (n << 4) + li;
          int c = (kblk << 2) + lg;
          int off = (r << 7) + ((c ^ (r & 7)) << 4);
          fbh[n] = *(const bf16x8*)((const char*)Bh + off);
        }
        #pragma unroll
        for (int m = 0; m < 4; ++m)
          #pragma unroll
          for (int n = 0; n < 4; ++n)
            acc[m][n] = __builtin_amdgcn_mfma_f32_16x16x32_bf16(fah[m], fbh[n], acc[m][n], 0, 0, 0);
      }
      __syncthreads();
    }

    // fold this tile's 4 cols/row into the per-lane running top-4 (branchless)
    const u32 colb = (u32)(col0 + wc + li);
    #pragma unroll
    for (int m = 0; m < 4; ++m)
      #pragma unroll
      for (int i = 0; i < 4; ++i) {
        u32 k0 = (__float_as_uint(fmaf(-2.f, acc[m][0][i], en0)) & 0xFFFFF800u) | colb;
        u32 k1 = (__float_as_uint(fmaf(-2.f, acc[m][1][i], en1)) & 0xFFFFF800u) | (colb + 16u);
        u32 k2 = (__float_as_uint(fmaf(-2.f, acc[m][2][i], en2)) & 0xFFFFF800u) | (colb + 32u);
        u32 k3 = (__float_as_uint(fmaf(-2.f, acc[m][3][i], en3)) & 0xFFFFF800u) | (colb + 48u);
        // sort4 ascending
        u32 a = min(k0, k1), b = max(k0, k1);
        u32 c = min(k2, k3), d = max(k2, k3);
        u32 e = min(a, c),  f = max(a, c);
        u32 g = min(b, d),  h = max(b, d);
        u32 q1 = e, q2 = min(f, g), q3 = max(f, g), q4 = h;
        MERGE4(cand[m * 4 + i][0], cand[m * 4 + i][1],
               cand[m * 4 + i][2], cand[m * 4 + i][3], q1, q2, q3, q4);
      }
  }

  // cross-li merge (16 lanes per row-group; lg preserved under xor<16)
  #pragma unroll
  for (int mi = 0; mi < 16; ++mi) {
    u32 s1 = cand[mi][0], s2 = cand[mi][1], s3 = cand[mi][2], s4 = cand[mi][3];
    #pragma unroll
    for (int off = 1; off <= 8; off <<= 1) {
      u32 o1 = __shfl_xor(s1, off), o2 = __shfl_xor(s2, off);
      u32 o3 = __shfl_xor(s3, off), o4 = __shfl_xor(s4, off);
      MERGE4(s1, s2, s3, s4, o1, o2, o3, o4);
    }
    cand[mi][0] = s1; cand[mi][1] = s2; cand[mi][2] = s3; cand[mi][3] = s4;
  }

  // cross wave-pair merge (w0<-w1, w2<-w3) via LDS, then store row top-4
  u32* ex = (u32*)Ah;                                // [128 rows][4]
  if ((w & 1) == 1 && li == 0) {
    #pragma unroll
    for (int m = 0; m < 4; ++m)
      #pragma unroll
      for (int i = 0; i < 4; ++i) {
        int lrow = wr + (m << 4) + (lg << 2) + i;    // C/D: row=(lane>>4)*4+reg
        uint4 v;
        v.x = cand[m * 4 + i][0]; v.y = cand[m * 4 + i][1];
        v.z = cand[m * 4 + i][2]; v.w = cand[m * 4 + i][3];
        *(uint4*)&ex[lrow << 2] = v;
      }
  }
  __syncthreads();
  if ((w & 1) == 0 && li == 0) {
    #pragma unroll
    for (int m = 0; m < 4; ++m)
      #pragma unroll
      for (int i = 0; i < 4; ++i) {
        int lrow = wr + (m << 4) + (lg << 2) + i;
        const u32* p = &ex[lrow << 2];
        u32 s1 = cand[m * 4 + i][0], s2 = cand[m * 4 + i][1];
        u32 s3 = cand[m * 4 + i][2], s4 = cand[m * 4 + i][3];
        u32 o1 = p[0], o2 = p[1], o3 = p[2], o4 = p[3];
        MERGE4(s1, s2, s3, s4, o1, o2, o3, o4);
        uint4 v; v.x = s1; v.y = s2; v.z = s3; v.w = s4;
        list[row0 + lrow] = v;
      }
  }
}

// ---- finalize argmin: 4 cands/row; fp64 rescore on near-ties ----
// also builds the cluster histogram (counts) for the counting sort.
__global__ void finalize_kernel(const uint4* __restrict__ list, const float* __restrict__ ze,
                                const float* __restrict__ emb, int* __restrict__ wsidx,
                                float* __restrict__ counts)
{
  int w = threadIdx.x >> 6, l = threadIdx.x & 63;
  int row = blockIdx.x * 4 + w;                      // grid 16384
  uint4 q = list[row];
  float d1 = __uint_as_float(q.x & 0xFFFFF800u);
  float lim = d1 + TAU;
  bool n2 = (q.y != 0xFFFFFFFFu) && (__uint_as_float(q.y & 0xFFFFF800u) < lim);
  bool n3 = (q.z != 0xFFFFFFFFu) && (__uint_as_float(q.z & 0xFFFFF800u) < lim);
  bool n4 = (q.w != 0xFFFFFFFFu) && (__uint_as_float(q.w & 0xFFFFF800u) < lim);
  int idx;
  if (!(n2 | n3 | n4)) {
    idx = (int)(q.x & 2047u);
  } else {
    double bd = 1e300; int bc = 0x7fffffff;
    const float* xr = ze + (((size_t)row) << 9);
    double xv[8];
    #pragma unroll
    for (int p = 0; p < 8; ++p) xv[p] = (double)xr[(l << 3) + p];
    #pragma unroll
    for (int j = 0; j < 4; ++j) {
      u32 kj = (j == 0) ? q.x : (j == 1) ? q.y : (j == 2) ? q.z : q.w;
      bool ok = (j == 0) || ((kj != 0xFFFFFFFFu) &&
                             (__uint_as_float(kj & 0xFFFFF800u) < lim));
      if (!ok) continue;
      int col = (int)(kj & 2047u);
      const float* er = emb + (((size_t)col) << 9);
      double s = 0.0;
      #pragma unroll
      for (int p = 0; p < 8; ++p) {
        double df = xv[p] - (double)er[(l << 3) + p];
        s += df * df;
      }
      #pragma unroll
      for (int off = 32; off >= 1; off >>= 1) s += __shfl_xor(s, off);
      if (s < bd || (s == bd && col < bc)) { bd = s; bc = col; }
    }
    idx = bc;
  }
  if (l == 0) {
    wsidx[row] = idx;
    atomicAdd(&counts[idx], 1.0f);
  }
}

// ---- single-block scan: offsets from counts, zero cursors, emit chunk list ----
__global__ void scan_kernel(const float* __restrict__ counts, u32* __restrict__ offsets,
                            u32* __restrict__ cursor, u32* __restrict__ chunkinfo,
                            u32* __restrict__ ntotal)
{
  int t = threadIdx.x;                               // 1 block, 256 threads
  int c[8]; int s = 0;
  #pragma unroll
  for (int i = 0; i < 8; ++i) { c[i] = (int)counts[t * 8 + i]; s += c[i]; }
  __shared__ int ts[256];
  ts[t] = s; __syncthreads();
  for (int off = 1; off < 256; off <<= 1) {
    int v = (t >= off) ? ts[t - off] : 0;
    __syncthreads();
    ts[t] += v;
    __syncthreads();
  }
  int run = ts[t] - s;                               // exclusive prefix
  int nch[8]; int ns = 0;
  #pragma unroll
  for (int i = 0; i < 8; ++i) {
    offsets[t * 8 + i] = (u32)run;
    cursor[t * 8 + i] = 0;
    run += c[i];
    nch[i] = (c[i] + CHUNK - 1) / CHUNK;
    ns += nch[i];
  }
  __shared__ int ts2[256];
  ts2[t] = ns; __syncthreads();
  for (int off = 1; off < 256; off <<= 1) {
    int v = (t >= off) ? ts2[t - off] : 0;
    __syncthreads();
    ts2[t] += v;
    __syncthreads();
  }
  int cb = ts2[t] - ns;
  #pragma unroll
  for (int i = 0; i < 8; ++i)
    for (int cc = 0; cc < nch[i]; ++cc)
      chunkinfo[cb++] = (u32)(t * 8 + i) | ((u32)cc << 11);
  if (t == 255) *ntotal = (u32)ts2[255];
}

// ---- scatter rows into cluster-sorted order ----
__global__ void scatter_kernel(const int* __restrict__ wsidx, const u32* __restrict__ offsets,
                               u32* __restrict__ cursor, u32* __restrict__ sorted)
{
  int row = blockIdx.x * 256 + threadIdx.x;          // grid 256
  int idx = wsidx[row];
  u32 pos = atomicAdd(&cursor[idx], 1u);
  sorted[offsets[idx] + pos] = (u32)row;
}

// ---- zero esum rows only where needed (empty or multi-chunk clusters) ----
__global__ void zesum_kernel(const float* __restrict__ counts, float* __restrict__ esum)
{
  int k = blockIdx.x;                                // grid 2048
  float c = counts[k];
  if (c == 0.0f || c > (float)CHUNK) {
    esum[((size_t)k << 9) + threadIdx.x] = 0.0f;
    esum[((size_t)k << 9) + 256 + threadIdx.x] = 0.0f;
  }
}

// ---- per-chunk fused: z_q write, idx, loss, segment sum (store; atomics only if >CHUNK) ----
__global__ __launch_bounds__(256)
void zq_seg_kernel(const float* __restrict__ ze, const float* __restrict__ emb,
                   const u32* __restrict__ offsets, const float* __restrict__ counts,
                   const u32* __restrict__ sorted, const u32* __restrict__ chunkinfo,
                   const u32* __restrict__ ntotal, float* __restrict__ o_zq,
                   float* __restrict__ o_idx, float* __restrict__ esum,
                   float* __restrict__ lossws)
{
  int cid = blockIdx.x;                              // grid MAXCHUNK
  if (cid >= (int)*ntotal) return;
  u32 rec = chunkinfo[cid];
  int k = rec & 2047, c = (int)(rec >> 11);
  int ctotal = (int)counts[k];
  int base = (int)offsets[k] + c * CHUNK;
  int cnt = min(ctotal - c * CHUNK, CHUNK);
  bool multi = ctotal > CHUNK;
  int t = threadIdx.x, w = t >> 6, l = t & 63;
  __shared__ u32 srow[CHUNK];
  __shared__ float sacc[4 * 512];
  __shared__ float sloss[4];
  if (t < cnt) srow[t] = sorted[base + t];
  __syncthreads();
  const float4* e4 = (const float4*)(emb + ((size_t)k << 9));
  float4 ev0 = e4[l * 2], ev1 = e4[l * 2 + 1];
  float a0x=0,a0y=0,a0z=0,a0w=0,a1x=0,a1y=0,a1z=0,a1w=0;
  float lacc = 0.f;
  for (int r = w; r < cnt; r += 4) {
    int row = (int)srow[r];
    const float4* z4 = (const float4*)(ze + ((size_t)row << 9));
    float4 zv0 = z4[l * 2], zv1 = z4[l * 2 + 1];
    float4 q0, q1;
    q0.x = zv0.x + (ev0.x - zv0.x);
    q0.y = zv0.y + (ev0.y - zv0.y);
    q0.z = zv0.z + (ev0.z - zv0.z);
    q0.w = zv0.w + (ev0.w - zv0.w);
    q1.x = zv1.x + (ev1.x - zv1.x);
    q1.y = zv1.y + (ev1.y - zv1.y);
    q1.z = zv1.z + (ev1.z - zv1.z);
    q1.w = zv1.w + (ev1.w - zv1.w);
    float4* zq4 = (float4*)(o_zq + ((size_t)row << 9));
    zq4[l * 2] = q0; zq4[l * 2 + 1] = q1;
    float dx = zv0.x - q0.x, dy = zv0.y - q0.y, dz = zv0.z - q0.z, dw = zv0.w - q0.w;
    lacc += dx*dx + dy*dy + dz*dz + dw*dw;
    dx = zv1.x - q1.x; dy = zv1.y - q1.y; dz = zv1.z - q1.z; dw = zv1.w - q1.w;
    lacc += dx*dx + dy*dy + dz*dz + dw*dw;
    a0x += zv0.x; a0y += zv0.y; a0z += zv0.z; a0w += zv0.w;
    a1x += zv1.x; a1y += zv1.y; a1z += zv1.z; a1w += zv1.w;
    if (l == 0) o_idx[row] = (float)k;
  }
  #pragma unroll
  for (int off = 32; off >= 1; off >>= 1) lacc += __shfl_xor(lacc, off);
  if (l == 0) sloss[w] = lacc;
  float* sa = sacc + w * 512 + l * 8;
  sa[0]=a0x; sa[1]=a0y; sa[2]=a0z; sa[3]=a0w; sa[4]=a1x; sa[5]=a1y; sa[6]=a1z; sa[7]=a1w;
  __syncthreads();
  #pragma unroll
  for (int j = 0; j < 2; ++j) {
    int col = t * 2 + j;
    float v = sacc[col] + sacc[512 + col] + sacc[1024 + col] + sacc[1536 + col];
    if (multi) atomicAdd(&esum[((size_t)k << 9) + col], v);
    else       esum[((size_t)k << 9) + col] = v;
  }
  if (t == 0) atomicAdd(lossws, sloss[0] + sloss[1] + sloss[2] + sloss[3]);
}

// ---- cluster-size EMA + smoothing factors + loss ----
__global__ void d1_kernel(const float* __restrict__ cs, const float* __restrict__ counts,
                          float* __restrict__ o_ncs, float* __restrict__ inv,
                          const float* __restrict__ lossws, float* __restrict__ o_loss)
{
  int t = threadIdx.x;                               // single block, 256 threads
  float ncs[8]; float s = 0.0f;
  #pragma unroll
  for (int i = 0; i < 8; ++i) {
    int k = t + (i << 8);
    float v = 0.99f * cs[k] + 0.01f * counts[k];
    ncs[i] = v; o_ncs[k] = v; s += v;
  }
  __shared__ float red[256];
  red[t] = s; __syncthreads();
  for (int h = 128; h >= 1; h >>= 1) { if (t < h) red[t] += red[t + h]; __syncthreads(); }
  float n = red[0];
  float denom = n + 2048.0f * 1e-5f;
  #pragma unroll
  for (int i = 0; i < 8; ++i) {
    int k = t + (i << 8);
    float sm = (ncs[i] + 1e-5f) / denom * n;
    inv[k] = 1.0f / sm;
  }
  if (t == 0) o_loss[0] = lossws[0] * 1.25f / 33554432.0f;
}

// ---- embed_avg EMA + new embedding ----
__global__ void d2_kernel(const float* __restrict__ ea, const float* __restrict__ inv,
                          float* __restrict__ o_emb, float* __restrict__ o_nea)
{
  int gid = blockIdx.x * 256 + threadIdx.x;          // grid 1024
  for (int i = gid; i < K_EMB * D_DIM; i += 1024 * 256) {
    float es = o_emb[i];                             // segment sum (scratch)
    float nea = 0.99f * ea[i] + 0.01f * es;
    o_nea[i] = nea;
    o_emb[i] = nea * inv[i >> 9];
  }
}

extern "C" void kernel_launch(void* const* d_in, const int* in_sizes, int n_in,
                              void* d_out, int out_size, void* d_ws, size_t ws_size,
                              hipStream_t stream)
{
  const float* ze  = (const float*)d_in[0];
  const float* emb = (const float*)d_in[1];
  const float* cs  = (const float*)d_in[2];
  const float* ea  = (const float*)d_in[3];
  float* out = (float*)d_out;
  float* o_zq   = out + OFF_ZQ;
  float* o_idx  = out + OFF_IDX;
  float* o_loss = out + OFF_LOSS;
  float* o_emb  = out + OFF_EMB;
  float* o_ncs  = out + OFF_NCS;
  float* o_nea  = out + OFF_NEA;
  // d_out self-scratch: bf16 z_e lives in the z_q section (64 MB, consumed
  // by dist_gemm before zq_seg overwrites it).
  ushort_t* xh = (ushort_t*)d_out;
  // workspace layout
  char* ws = (char*)d_ws;
  ushort_t* ehp = (ushort_t*)ws;                     // 2 MB
  int* wsidx    = (int*)(ws + 2097152);              // 256 KB
  float* counts = (float*)(ws + 2097152 + 262144);   // 8 KB
  float* enorm  = counts + 2048;                     // 8 KB
  float* inv    = enorm + 2048;                      // 8 KB
  float* lossws = inv + 2048;                        // 4 B (+pad)
  u32* offsets  = (u32*)(lossws + 64);               // 8 KB
  u32* cursor   = offsets + 2048;                    // 8 KB
  u32* sorted   = cursor + 2048;                     // 256 KB
  u32* chunkinfo= sorted + 65536;                    // 10 KB
  u32* ntotal   = chunkinfo + MAXCHUNK;              // 4 B
  uint4* list   = (uint4*)(ws + 3145728);            // 1 MB, [65536] uint4

  prep_z_kernel<<<8192, 256, 0, stream>>>(ze, xh, counts, lossws);
  prep_e_kernel<<<512, 256, 0, stream>>>(emb, ehp, enorm);
  dist_gemm<<<512, 256, 0, stream>>>(xh, ehp, enorm, list);
  finalize_kernel<<<16384, 256, 0, stream>>>(list, ze, emb, wsidx, counts);
  scan_kernel<<<1, 256, 0, stream>>>(counts, offsets, cursor, chunkinfo, ntotal);
  scatter_kernel<<<256, 256, 0, stream>>>(wsidx, offsets, cursor, sorted);
  zesum_kernel<<<2048, 256, 0, stream>>>(counts, o_emb);
  zq_seg_kernel<<<MAXCHUNK, 256, 0, stream>>>(ze, emb, offsets, counts, sorted,
                                              chunkinfo, ntotal, o_zq, o_idx, o_emb, lossws);
  d1_kernel<<<1, 256, 0, stream>>>(cs, counts, o_ncs, inv, lossws, o_loss);
  d2_kernel<<<1024, 256, 0, stream>>>(ea, inv, o_emb, o_nea);
}